// Round 1
// baseline (619.873 us; speedup 1.0000x reference)
//
#include <hip/hip_runtime.h>
#include <hip/hip_bf16.h>
#include <math.h>

#define Bb 64
#define Nn 8192
#define MWw 128
#define Hh 8
#define Cc 1024
#define HDd 128
#define Kk 3

__device__ __forceinline__ float dot4(float4 a, float4 b) {
  return a.x*b.x + a.y*b.y + a.z*b.z + a.w*b.w;
}
__device__ __forceinline__ float sigmoidf_(float x) { return 1.0f / (1.0f + __expf(-x)); }
__device__ __forceinline__ float softplusf_(float x) {
  return fmaxf(x, 0.0f) + log1pf(__expf(-fabsf(x)));
}

// ---------------------------------------------------------------------------
// K1: heads = cs @ W_head (+b), then per-(b,h): key vector, reset/beta/gate/
// gamma/shift params, ||key||. One block per (b,h), 128 threads.
// ---------------------------------------------------------------------------
__global__ __launch_bounds__(128) void k_params(
    const float* __restrict__ cs, const float* __restrict__ W_head, const float* __restrict__ b_head,
    const float* __restrict__ W_reset, const float* __restrict__ b_reset,
    const float* __restrict__ W_key, const float* __restrict__ b_key,
    const float* __restrict__ W_beta, const float* __restrict__ b_beta,
    const float* __restrict__ W_gate, const float* __restrict__ b_gate,
    const float* __restrict__ W_shift, const float* __restrict__ b_shift,
    const float* __restrict__ W_gamma, const float* __restrict__ b_gamma,
    float* __restrict__ key_ws, float* __restrict__ params)
{
  int bh = blockIdx.x;
  int b = bh >> 3, h = bh & 7;
  int t = threadIdx.x;
  __shared__ float head_s[HDd];
  __shared__ float red[8][HDd];

  const float* csb = cs + b * Cc;
  float acc = b_head[h * HDd + t];
  const float* wcol = W_head + h * HDd + t;
  #pragma unroll 4
  for (int c = 0; c < Cc; ++c) acc = fmaf(csb[c], wcol[(size_t)c * (Hh * HDd)], acc);
  head_s[t] = acc;
  __syncthreads();

  float kv = b_key[h * MWw + t];
  const float* wk = W_key + h * HDd * MWw + t;
  #pragma unroll 4
  for (int d = 0; d < HDd; ++d) kv = fmaf(head_s[d], wk[d * MWw], kv);
  key_ws[bh * MWw + t] = kv;

  float hd = head_s[t];
  red[0][t] = hd * W_reset[h * HDd + t];
  red[1][t] = hd * W_beta[h * HDd + t];
  red[2][t] = hd * W_gate[h * HDd + t];
  red[3][t] = hd * W_gamma[h * HDd + t];
  red[4][t] = hd * W_shift[(h * HDd + t) * Kk + 0];
  red[5][t] = hd * W_shift[(h * HDd + t) * Kk + 1];
  red[6][t] = hd * W_shift[(h * HDd + t) * Kk + 2];
  red[7][t] = kv * kv;
  __syncthreads();
  for (int s = 64; s > 0; s >>= 1) {
    if (t < s) {
      #pragma unroll
      for (int j = 0; j < 8; ++j) red[j][t] += red[j][t + s];
    }
    __syncthreads();
  }
  if (t == 0) {
    float reset = sigmoidf_(red[0][0] + b_reset[h]);
    float beta  = softplusf_(red[1][0] + b_beta[h]);
    float gate  = sigmoidf_(red[2][0] + b_gate[h]);
    float gamma = 1.0f + softplusf_(red[3][0] + b_gamma[h]);
    float a0 = red[4][0] + b_shift[h * Kk + 0];
    float a1 = red[5][0] + b_shift[h * Kk + 1];
    float a2 = red[6][0] + b_shift[h * Kk + 2];
    float mx = fmaxf(a0, fmaxf(a1, a2));
    float e0 = __expf(a0 - mx), e1 = __expf(a1 - mx), e2 = __expf(a2 - mx);
    float inv = 1.0f / (e0 + e1 + e2);
    float* P = params + bh * 8;
    P[0] = reset; P[1] = beta; P[2] = gate; P[3] = gamma;
    P[4] = e0 * inv; P[5] = e1 * inv; P[6] = e2 * inv;
    P[7] = sqrtf(red[7][0]);
  }
}

// ---------------------------------------------------------------------------
// K2: big pass 1 over memory. 8 lanes per row; lane sub covers float4 indices
// {sub, sub+8, sub+16, sub+24}. Keys broadcast from LDS. Transpose-butterfly
// reduce leaves lane sub with head sub's full dot. e = exp(beta*cos - beta)
// (cos<=1 so beta is a valid softmax shift -> no max pass). atomicAdd Z.
// ---------------------------------------------------------------------------
__global__ __launch_bounds__(256) void k_sim(
    const float* __restrict__ mem, const float* __restrict__ key_ws,
    const float* __restrict__ params, float* __restrict__ e_ws, float* __restrict__ Z)
{
  int b = blockIdx.y, chunk = blockIdx.x;
  int t = threadIdx.x;
  int sub = t & 7, rid = t >> 3;
  __shared__ float4 keys[8][32];
  __shared__ float betas[8], knorms[8];
  if (t < 8) { betas[t] = params[(b * 8 + t) * 8 + 1]; knorms[t] = params[(b * 8 + t) * 8 + 7]; }
  {
    int h = t >> 5, q = t & 31;
    keys[h][q] = ((const float4*)key_ws)[(b * 8 + h) * 32 + q];
  }
  __syncthreads();

  const float4* m4 = (const float4*)mem + (size_t)b * Nn * 32;
  float zloc = 0.0f;
  int n0 = chunk * 256;
  float beta = betas[sub], kn = knorms[sub];

  for (int it = 0; it < 8; ++it) {
    int n = n0 + it * 32 + rid;
    const float4* rp = m4 + (size_t)n * 32 + sub;
    float4 m0 = rp[0], m1 = rp[8], m2 = rp[16], m3 = rp[24];
    float nrm = dot4(m0, m0) + dot4(m1, m1) + dot4(m2, m2) + dot4(m3, m3);
    float acc[8];
    #pragma unroll
    for (int h2 = 0; h2 < 8; ++h2) {
      float4 k0 = keys[h2][sub], k1 = keys[h2][sub + 8], k2 = keys[h2][sub + 16], k3 = keys[h2][sub + 24];
      acc[h2] = dot4(m0, k0) + dot4(m1, k1) + dot4(m2, k2) + dot4(m3, k3);
    }
    // transpose-reduce over the 8 lanes of this row: lane sub ends with head sub
    float v4[4];
    {
      bool hi = (sub & 1) != 0;
      #pragma unroll
      for (int j = 0; j < 4; ++j) {
        float keep = hi ? acc[2 * j + 1] : acc[2 * j];
        float send = hi ? acc[2 * j] : acc[2 * j + 1];
        v4[j] = keep + __shfl_xor(send, 1, 64);
      }
    }
    float v2[2];
    {
      bool hi = (sub & 2) != 0;
      #pragma unroll
      for (int j = 0; j < 2; ++j) {
        float keep = hi ? v4[2 * j + 1] : v4[2 * j];
        float send = hi ? v4[2 * j] : v4[2 * j + 1];
        v2[j] = keep + __shfl_xor(send, 2, 64);
      }
    }
    float d;
    {
      bool hi = (sub & 4) != 0;
      float keep = hi ? v2[1] : v2[0];
      float send = hi ? v2[0] : v2[1];
      d = keep + __shfl_xor(send, 4, 64);
    }
    nrm += __shfl_xor(nrm, 1, 64);
    nrm += __shfl_xor(nrm, 2, 64);
    nrm += __shfl_xor(nrm, 4, 64);

    float s = beta * d / (kn * sqrtf(nrm) + 1e-8f);
    float e = __expf(s - beta);
    e_ws[(size_t)(b * 8 + sub) * Nn + n] = e;
    zloc += e;
  }
  zloc += __shfl_xor(zloc, 8, 64);
  zloc += __shfl_xor(zloc, 16, 64);
  zloc += __shfl_xor(zloc, 32, 64);
  if ((t & 63) < 8) atomicAdd(&Z[b * 8 + sub], zloc);
}

// ---------------------------------------------------------------------------
// K3: w_g blend + circular conv (K=3) + gamma power. One block per
// (b,h,chunk of 2048). LDS tile with halo handles circular roll. atomicAdd S.
// w_pow written straight into d_out's new_w region (normalized in K4a).
// ---------------------------------------------------------------------------
__global__ __launch_bounds__(256) void k_conv(
    const float* __restrict__ e_ws, const float* __restrict__ prev, const float* __restrict__ defw,
    const float* __restrict__ params, const float* __restrict__ Z,
    float* __restrict__ wp, float* __restrict__ S)
{
  int chunk = blockIdx.x, h = blockIdx.y, b = blockIdx.z;
  int bh = b * 8 + h, t = threadIdx.x;
  __shared__ float wg[2050];
  const float* P = params + bh * 8;
  float reset = P[0], gate = P[2], gamma = P[3], s0 = P[4], s1 = P[5], s2 = P[6];
  float invZg = gate / Z[bh];
  float om = 1.0f - gate, omr = 1.0f - reset;
  size_t base = (size_t)bh * Nn;
  int n0 = chunk * 2048;

  for (int it = 0; it < 8; ++it) {
    int l = it * 256 + t;
    int n = n0 + l;
    float e = e_ws[base + n], pv = prev[base + n], dv = defw[base + n];
    wg[1 + l] = invZg * e + om * (pv * omr + dv * reset);
  }
  if (t < 2) {
    int n = (t == 0) ? ((n0 + Nn - 1) & (Nn - 1)) : ((n0 + 2048) & (Nn - 1));
    float e = e_ws[base + n], pv = prev[base + n], dv = defw[base + n];
    wg[(t == 0) ? 0 : 2049] = invZg * e + om * (pv * omr + dv * reset);
  }
  __syncthreads();

  float sacc = 0.0f;
  for (int it = 0; it < 8; ++it) {
    int l = it * 256 + t;
    // w_s[n] = s0*wg[n+1] + s1*wg[n] + s2*wg[n-1]  (jnp.roll semantics)
    float wsv = s0 * wg[l + 2] + s1 * wg[l + 1] + s2 * wg[l];
    float wpv = __expf(gamma * __logf(wsv + 1e-8f));
    wp[base + n0 + l] = wpv;
    sacc += wpv;
  }
  sacc += __shfl_xor(sacc, 1, 64);
  sacc += __shfl_xor(sacc, 2, 64);
  sacc += __shfl_xor(sacc, 4, 64);
  sacc += __shfl_xor(sacc, 8, 64);
  sacc += __shfl_xor(sacc, 16, 64);
  sacc += __shfl_xor(sacc, 32, 64);
  __shared__ float sred[4];
  if ((t & 63) == 0) sred[t >> 6] = sacc;
  __syncthreads();
  if (t == 0) atomicAdd(&S[bh], sred[0] + sred[1] + sred[2] + sred[3]);
}

// ---------------------------------------------------------------------------
// K4a: new_w = w_pow / S (in place in d_out), coef[b,n] = sum_h merge_h*new_w
// ---------------------------------------------------------------------------
__global__ __launch_bounds__(256) void k_norm(
    float* __restrict__ wp, const float* __restrict__ S, const float* __restrict__ merge_w,
    float* __restrict__ coef)
{
  int b = blockIdx.y; int n0 = blockIdx.x * 2048; int t = threadIdx.x;
  __shared__ float invS[8], mw[8];
  if (t < 8) { invS[t] = 1.0f / S[b * 8 + t]; mw[t] = merge_w[t]; }
  __syncthreads();
  for (int it = 0; it < 8; ++it) {
    int n = n0 + it * 256 + t;
    float cf = 0.0f;
    #pragma unroll
    for (int h = 0; h < 8; ++h) {
      size_t idx = (size_t)(b * 8 + h) * Nn + n;
      float v = wp[idx] * invS[h];
      wp[idx] = v;
      cf = fmaf(mw[h], v, cf);
    }
    coef[(size_t)b * Nn + n] = cf;
  }
}

// ---------------------------------------------------------------------------
// K4b: big pass 2 over memory: out[b,:] += sum_n coef[b,n] * mem[b,n,:]
// (fused per-head read + merge). float4 coalesced; LDS reduce; 128 atomics.
// ---------------------------------------------------------------------------
__global__ __launch_bounds__(256) void k_read(
    const float* __restrict__ mem, const float* __restrict__ coef, float* __restrict__ out)
{
  int b = blockIdx.y; int n0 = blockIdx.x * 512; int t = threadIdx.x;
  int w4 = t & 31, rg = t >> 5;
  const float4* m4 = (const float4*)mem + (size_t)b * Nn * 32;
  const float* cf = coef + (size_t)b * Nn;
  float4 acc = make_float4(0.0f, 0.0f, 0.0f, 0.0f);
  #pragma unroll 4
  for (int it = 0; it < 64; ++it) {
    int n = n0 + it * 8 + rg;
    float c = cf[n];
    float4 m = m4[(size_t)n * 32 + w4];
    acc.x = fmaf(c, m.x, acc.x);
    acc.y = fmaf(c, m.y, acc.y);
    acc.z = fmaf(c, m.z, acc.z);
    acc.w = fmaf(c, m.w, acc.w);
  }
  __shared__ float4 red4[256];
  red4[t] = acc;
  __syncthreads();
  if (t < 32) {
    float4 s = red4[t];
    #pragma unroll
    for (int j = 1; j < 8; ++j) {
      float4 o = red4[t + 32 * j];
      s.x += o.x; s.y += o.y; s.z += o.z; s.w += o.w;
    }
    atomicAdd(&out[b * MWw + t * 4 + 0], s.x);
    atomicAdd(&out[b * MWw + t * 4 + 1], s.y);
    atomicAdd(&out[b * MWw + t * 4 + 2], s.z);
    atomicAdd(&out[b * MWw + t * 4 + 3], s.w);
  }
}

extern "C" void kernel_launch(void* const* d_in, const int* in_sizes, int n_in,
                              void* d_out, int out_size, void* d_ws, size_t ws_size,
                              hipStream_t stream)
{
  const float* cs      = (const float*)d_in[0];
  const float* mem     = (const float*)d_in[1];
  const float* prev    = (const float*)d_in[2];
  const float* defw    = (const float*)d_in[3];
  const float* W_head  = (const float*)d_in[4];
  const float* b_head  = (const float*)d_in[5];
  const float* W_reset = (const float*)d_in[6];
  const float* b_reset = (const float*)d_in[7];
  const float* W_key   = (const float*)d_in[8];
  const float* b_key   = (const float*)d_in[9];
  const float* W_beta  = (const float*)d_in[10];
  const float* b_beta  = (const float*)d_in[11];
  const float* W_gate  = (const float*)d_in[12];
  const float* b_gate  = (const float*)d_in[13];
  const float* W_shift = (const float*)d_in[14];
  const float* b_shift = (const float*)d_in[15];
  const float* W_gamma = (const float*)d_in[16];
  const float* b_gamma = (const float*)d_in[17];
  const float* merge_w = (const float*)d_in[18];

  float* out  = (float*)d_out;          // [B,MW] = 8192 floats
  float* neww = out + Bb * MWw;         // [B,H,N] — used as w_pow scratch then final

  float* ws_f   = (float*)d_ws;
  float* key_ws = ws_f;                     // 65536 floats
  float* params = ws_f + 65536;             // 4096
  float* Zacc   = ws_f + 69632;             // 512
  float* Sacc   = ws_f + 70144;             // 512
  float* e_ws   = ws_f + 70656;             // 4194304
  float* coef   = ws_f + 70656 + 4194304;   // 524288
  // total ws usage: ~19.2 MB

  hipMemsetAsync(Zacc, 0, 1024 * sizeof(float), stream);           // Z and S
  hipMemsetAsync(out, 0, Bb * MWw * sizeof(float), stream);        // out accumulator

  k_params<<<dim3(Bb * Hh), dim3(128), 0, stream>>>(
      cs, W_head, b_head, W_reset, b_reset, W_key, b_key, W_beta, b_beta,
      W_gate, b_gate, W_shift, b_shift, W_gamma, b_gamma, key_ws, params);
  k_sim<<<dim3(32, Bb), dim3(256), 0, stream>>>(mem, key_ws, params, e_ws, Zacc);
  k_conv<<<dim3(4, Hh, Bb), dim3(256), 0, stream>>>(e_ws, prev, defw, params, Zacc, neww, Sacc);
  k_norm<<<dim3(4, Bb), dim3(256), 0, stream>>>(neww, Sacc, merge_w, coef);
  k_read<<<dim3(16, Bb), dim3(256), 0, stream>>>(mem, coef, out);
}

// Round 2
// 505.589 us; speedup vs baseline: 1.2260x; 1.2260x over previous
//
#include <hip/hip_runtime.h>
#include <hip/hip_bf16.h>
#include <math.h>

#define Bb 64
#define Nn 8192
#define MWw 128
#define Hh 8
#define Cc 1024
#define HDd 128
#define Kk 3

__device__ __forceinline__ float dot4(float4 a, float4 b) {
  return a.x*b.x + a.y*b.y + a.z*b.z + a.w*b.w;
}
__device__ __forceinline__ float sigmoidf_(float x) { return 1.0f / (1.0f + __expf(-x)); }
__device__ __forceinline__ float softplusf_(float x) {
  return fmaxf(x, 0.0f) + log1pf(__expf(-fabsf(x)));
}

// ---------------------------------------------------------------------------
// K1: one block per (b,h), 1024 threads. K-dim split 8 ways (slice = t>>7),
// LDS tree reduce. Serial chain is 128 iterations, not 1024.
// ---------------------------------------------------------------------------
__global__ __launch_bounds__(1024) void k_params(
    const float* __restrict__ cs, const float* __restrict__ W_head, const float* __restrict__ b_head,
    const float* __restrict__ W_reset, const float* __restrict__ b_reset,
    const float* __restrict__ W_key, const float* __restrict__ b_key,
    const float* __restrict__ W_beta, const float* __restrict__ b_beta,
    const float* __restrict__ W_gate, const float* __restrict__ b_gate,
    const float* __restrict__ W_shift, const float* __restrict__ b_shift,
    const float* __restrict__ W_gamma, const float* __restrict__ b_gamma,
    float* __restrict__ key_ws, float* __restrict__ params)
{
  int bh = blockIdx.x;
  int b = bh >> 3, h = bh & 7;
  int t = threadIdx.x;
  int d = t & 127, sl = t >> 7;   // 8 slices
  __shared__ float red[8][128];
  __shared__ float head_s[128];
  __shared__ float key_s[128];

  // --- heads[d] = sum_c cs[b,c] * W_head[c, h*128+d]  (+b_head) ---
  const float* csb = cs + b * Cc + sl * 128;
  const float* w0 = W_head + (size_t)(sl * 128) * (Hh * HDd) + h * HDd + d;
  float acc = 0.0f;
  #pragma unroll 8
  for (int c = 0; c < 128; ++c) acc = fmaf(csb[c], w0[(size_t)c * (Hh * HDd)], acc);
  red[sl][d] = acc;
  __syncthreads();
  if (t < 128) {
    float s = b_head[h * HDd + t];
    #pragma unroll
    for (int j = 0; j < 8; ++j) s += red[j][t];
    head_s[t] = s;
  }
  __syncthreads();

  // --- key[w] = sum_d head[d] * W_key[h,d,w]  (+b_key) ---
  {
    const float* wk = W_key + (size_t)h * HDd * MWw + (sl * 16) * MWw + d;
    float ka = 0.0f;
    #pragma unroll
    for (int dd = 0; dd < 16; ++dd) ka = fmaf(head_s[sl * 16 + dd], wk[dd * MWw], ka);
    red[sl][d] = ka;
  }
  __syncthreads();
  if (t < 128) {
    float kv = b_key[h * MWw + t];
    #pragma unroll
    for (int j = 0; j < 8; ++j) kv += red[j][t];
    key_ws[bh * MWw + t] = kv;
    key_s[t] = kv;
  }
  __syncthreads();

  // --- 8 parallel dot-128 reductions: reset/beta/gate/gamma/shift0..2/||key||^2
  float hd = head_s[d];
  float v;
  switch (sl) {
    case 0: v = hd * W_reset[h * HDd + d]; break;
    case 1: v = hd * W_beta[h * HDd + d]; break;
    case 2: v = hd * W_gate[h * HDd + d]; break;
    case 3: v = hd * W_gamma[h * HDd + d]; break;
    case 4: v = hd * W_shift[(h * HDd + d) * Kk + 0]; break;
    case 5: v = hd * W_shift[(h * HDd + d) * Kk + 1]; break;
    case 6: v = hd * W_shift[(h * HDd + d) * Kk + 2]; break;
    default: v = key_s[d] * key_s[d]; break;
  }
  red[sl][d] = v;
  __syncthreads();
  for (int s = 64; s > 0; s >>= 1) {
    if (d < s) red[sl][d] += red[sl][d + s];
    __syncthreads();
  }
  if (t == 0) {
    float reset = sigmoidf_(red[0][0] + b_reset[h]);
    float beta  = softplusf_(red[1][0] + b_beta[h]);
    float gate  = sigmoidf_(red[2][0] + b_gate[h]);
    float gamma = 1.0f + softplusf_(red[3][0] + b_gamma[h]);
    float a0 = red[4][0] + b_shift[h * Kk + 0];
    float a1 = red[5][0] + b_shift[h * Kk + 1];
    float a2 = red[6][0] + b_shift[h * Kk + 2];
    float mx = fmaxf(a0, fmaxf(a1, a2));
    float e0 = __expf(a0 - mx), e1 = __expf(a1 - mx), e2 = __expf(a2 - mx);
    float inv = 1.0f / (e0 + e1 + e2);
    float* P = params + bh * 8;
    P[0] = reset; P[1] = beta; P[2] = gate; P[3] = gamma;
    P[4] = e0 * inv; P[5] = e1 * inv; P[6] = e2 * inv;
    P[7] = sqrtf(red[7][0]);
  }
}

// ---------------------------------------------------------------------------
// K2: big pass 1 over memory. 8 lanes per row (sub covers float4 cols
// {sub,sub+8,sub+16,sub+24}). ALL 8 heads' key fragments hand-hoisted into
// exactly 128 VGPRs (loaded once). T=2 row-steps per iteration;
// #pragma unroll 1 on the outer loop keeps VGPR ~200 (no spill, 2 waves/EU).
// Transpose-butterfly (7 shfl / 8 rows) leaves lane sub with head sub's dot.
// e = exp(beta*cos - beta) -> no max pass. atomicAdd Z.
// ---------------------------------------------------------------------------
__global__ __launch_bounds__(256, 2) void k_sim(
    const float* __restrict__ mem, const float* __restrict__ key_ws,
    const float* __restrict__ params, float* __restrict__ e_ws, float* __restrict__ Z)
{
  int b = blockIdx.y, chunk = blockIdx.x;
  int t = threadIdx.x;
  int lane = t & 63, wid = t >> 6;
  int sub = lane & 7, rid = lane >> 3;
  __shared__ float4 keys[8][32];
  __shared__ float betas[8], knorms[8];
  if (t < 8) { betas[t] = params[(b * 8 + t) * 8 + 1]; knorms[t] = params[(b * 8 + t) * 8 + 7]; }
  {
    int h = t >> 5, q = t & 31;
    keys[h][q] = ((const float4*)key_ws)[(b * 8 + h) * 32 + q];
  }
  __syncthreads();

  // hand-hoisted keys: 8 heads x 4 float4 = 128 VGPRs, loaded once
  float4 kreg[8][4];
  #pragma unroll
  for (int h2 = 0; h2 < 8; ++h2) {
    kreg[h2][0] = keys[h2][sub];
    kreg[h2][1] = keys[h2][sub + 8];
    kreg[h2][2] = keys[h2][sub + 16];
    kreg[h2][3] = keys[h2][sub + 24];
  }

  const float4* m4 = (const float4*)mem + (size_t)b * Nn * 32;
  float beta = betas[sub], kn = knorms[sub];
  float zloc = 0.0f;
  int n0 = chunk * 512;

  #pragma unroll 1
  for (int itr = 0; itr < 8; ++itr) {
    int nb = n0 + itr * 64 + wid * 16 + rid;  // row for (r=0); r adds 8
    float4 m[2][4];
    float nrm[2];
    float acc[2][8];
    #pragma unroll
    for (int r = 0; r < 2; ++r) {
      const float4* rp = m4 + (size_t)(nb + r * 8) * 32 + sub;
      m[r][0] = rp[0]; m[r][1] = rp[8]; m[r][2] = rp[16]; m[r][3] = rp[24];
    }
    #pragma unroll
    for (int r = 0; r < 2; ++r) {
      nrm[r] = dot4(m[r][0], m[r][0]) + dot4(m[r][1], m[r][1])
             + dot4(m[r][2], m[r][2]) + dot4(m[r][3], m[r][3]);
      #pragma unroll
      for (int h2 = 0; h2 < 8; ++h2) {
        acc[r][h2] = dot4(m[r][0], kreg[h2][0]) + dot4(m[r][1], kreg[h2][1])
                   + dot4(m[r][2], kreg[h2][2]) + dot4(m[r][3], kreg[h2][3]);
      }
    }
    #pragma unroll
    for (int r = 0; r < 2; ++r) {
      float* a = acc[r];
      bool h1 = (sub & 1) != 0;
      float v40 = (h1 ? a[1] : a[0]) + __shfl_xor(h1 ? a[0] : a[1], 1, 64);
      float v41 = (h1 ? a[3] : a[2]) + __shfl_xor(h1 ? a[2] : a[3], 1, 64);
      float v42 = (h1 ? a[5] : a[4]) + __shfl_xor(h1 ? a[4] : a[5], 1, 64);
      float v43 = (h1 ? a[7] : a[6]) + __shfl_xor(h1 ? a[6] : a[7], 1, 64);
      bool h2b = (sub & 2) != 0;
      float v20 = (h2b ? v41 : v40) + __shfl_xor(h2b ? v40 : v41, 2, 64);
      float v21 = (h2b ? v43 : v42) + __shfl_xor(h2b ? v42 : v43, 2, 64);
      bool h4 = (sub & 4) != 0;
      float dsum = (h4 ? v21 : v20) + __shfl_xor(h4 ? v20 : v21, 4, 64);
      float nr = nrm[r];
      nr += __shfl_xor(nr, 1, 64);
      nr += __shfl_xor(nr, 2, 64);
      nr += __shfl_xor(nr, 4, 64);
      float s = beta * dsum / (kn * sqrtf(nr) + 1e-8f);
      float e = __expf(s - beta);
      e_ws[(size_t)(b * 8 + sub) * Nn + (nb + r * 8)] = e;
      zloc += e;
    }
  }
  zloc += __shfl_xor(zloc, 8, 64);
  zloc += __shfl_xor(zloc, 16, 64);
  zloc += __shfl_xor(zloc, 32, 64);
  if (lane < 8) atomicAdd(&Z[b * 8 + lane], zloc);
}

// ---------------------------------------------------------------------------
// K3: w_g blend + circular conv (K=3) + gamma power. LDS tile with halo.
// w_pow written into d_out's new_w region (normalized in K4a). atomicAdd S.
// ---------------------------------------------------------------------------
__global__ __launch_bounds__(256) void k_conv(
    const float* __restrict__ e_ws, const float* __restrict__ prev, const float* __restrict__ defw,
    const float* __restrict__ params, const float* __restrict__ Z,
    float* __restrict__ wp, float* __restrict__ S)
{
  int chunk = blockIdx.x, h = blockIdx.y, b = blockIdx.z;
  int bh = b * 8 + h, t = threadIdx.x;
  __shared__ float wg[2050];
  const float* P = params + bh * 8;
  float reset = P[0], gate = P[2], gamma = P[3], s0 = P[4], s1 = P[5], s2 = P[6];
  float invZg = gate / Z[bh];
  float om = 1.0f - gate, omr = 1.0f - reset;
  size_t base = (size_t)bh * Nn;
  int n0 = chunk * 2048;

  for (int it = 0; it < 8; ++it) {
    int l = it * 256 + t;
    int n = n0 + l;
    float e = e_ws[base + n], pv = prev[base + n], dv = defw[base + n];
    wg[1 + l] = invZg * e + om * (pv * omr + dv * reset);
  }
  if (t < 2) {
    int n = (t == 0) ? ((n0 + Nn - 1) & (Nn - 1)) : ((n0 + 2048) & (Nn - 1));
    float e = e_ws[base + n], pv = prev[base + n], dv = defw[base + n];
    wg[(t == 0) ? 0 : 2049] = invZg * e + om * (pv * omr + dv * reset);
  }
  __syncthreads();

  float sacc = 0.0f;
  for (int it = 0; it < 8; ++it) {
    int l = it * 256 + t;
    // w_s[n] = s0*wg[n+1] + s1*wg[n] + s2*wg[n-1]  (jnp.roll semantics)
    float wsv = s0 * wg[l + 2] + s1 * wg[l + 1] + s2 * wg[l];
    float wpv = __expf(gamma * __logf(wsv + 1e-8f));
    wp[base + n0 + l] = wpv;
    sacc += wpv;
  }
  sacc += __shfl_xor(sacc, 1, 64);
  sacc += __shfl_xor(sacc, 2, 64);
  sacc += __shfl_xor(sacc, 4, 64);
  sacc += __shfl_xor(sacc, 8, 64);
  sacc += __shfl_xor(sacc, 16, 64);
  sacc += __shfl_xor(sacc, 32, 64);
  __shared__ float sred[4];
  if ((t & 63) == 0) sred[t >> 6] = sacc;
  __syncthreads();
  if (t == 0) atomicAdd(&S[bh], sred[0] + sred[1] + sred[2] + sred[3]);
}

// ---------------------------------------------------------------------------
// K4a: new_w = w_pow / S (in place in d_out), coef[b,n] = sum_h merge_h*new_w
// ---------------------------------------------------------------------------
__global__ __launch_bounds__(256) void k_norm(
    float* __restrict__ wp, const float* __restrict__ S, const float* __restrict__ merge_w,
    float* __restrict__ coef)
{
  int b = blockIdx.y; int n0 = blockIdx.x * 1024; int t = threadIdx.x;
  __shared__ float invS[8], mw[8];
  if (t < 8) { invS[t] = 1.0f / S[b * 8 + t]; mw[t] = merge_w[t]; }
  __syncthreads();
  for (int it = 0; it < 4; ++it) {
    int n = n0 + it * 256 + t;
    float cf = 0.0f;
    #pragma unroll
    for (int h = 0; h < 8; ++h) {
      size_t idx = (size_t)(b * 8 + h) * Nn + n;
      float v = wp[idx] * invS[h];
      wp[idx] = v;
      cf = fmaf(mw[h], v, cf);
    }
    coef[(size_t)b * Nn + n] = cf;
  }
}

// ---------------------------------------------------------------------------
// K4b: big pass 2: out[b,:] += sum_n coef[b,n] * mem[b,n,:]
// ---------------------------------------------------------------------------
__global__ __launch_bounds__(256) void k_read(
    const float* __restrict__ mem, const float* __restrict__ coef, float* __restrict__ out)
{
  int b = blockIdx.y; int n0 = blockIdx.x * 512; int t = threadIdx.x;
  int w4 = t & 31, rg = t >> 5;
  const float4* m4 = (const float4*)mem + (size_t)b * Nn * 32;
  const float* cf = coef + (size_t)b * Nn;
  float4 acc = make_float4(0.0f, 0.0f, 0.0f, 0.0f);
  #pragma unroll 4
  for (int it = 0; it < 64; ++it) {
    int n = n0 + it * 8 + rg;
    float c = cf[n];
    float4 m = m4[(size_t)n * 32 + w4];
    acc.x = fmaf(c, m.x, acc.x);
    acc.y = fmaf(c, m.y, acc.y);
    acc.z = fmaf(c, m.z, acc.z);
    acc.w = fmaf(c, m.w, acc.w);
  }
  __shared__ float4 red4[256];
  red4[t] = acc;
  __syncthreads();
  if (t < 32) {
    float4 s = red4[t];
    #pragma unroll
    for (int j = 1; j < 8; ++j) {
      float4 o = red4[t + 32 * j];
      s.x += o.x; s.y += o.y; s.z += o.z; s.w += o.w;
    }
    atomicAdd(&out[b * MWw + t * 4 + 0], s.x);
    atomicAdd(&out[b * MWw + t * 4 + 1], s.y);
    atomicAdd(&out[b * MWw + t * 4 + 2], s.z);
    atomicAdd(&out[b * MWw + t * 4 + 3], s.w);
  }
}

extern "C" void kernel_launch(void* const* d_in, const int* in_sizes, int n_in,
                              void* d_out, int out_size, void* d_ws, size_t ws_size,
                              hipStream_t stream)
{
  const float* cs      = (const float*)d_in[0];
  const float* mem     = (const float*)d_in[1];
  const float* prev    = (const float*)d_in[2];
  const float* defw    = (const float*)d_in[3];
  const float* W_head  = (const float*)d_in[4];
  const float* b_head  = (const float*)d_in[5];
  const float* W_reset = (const float*)d_in[6];
  const float* b_reset = (const float*)d_in[7];
  const float* W_key   = (const float*)d_in[8];
  const float* b_key   = (const float*)d_in[9];
  const float* W_beta  = (const float*)d_in[10];
  const float* b_beta  = (const float*)d_in[11];
  const float* W_gate  = (const float*)d_in[12];
  const float* b_gate  = (const float*)d_in[13];
  const float* W_shift = (const float*)d_in[14];
  const float* b_shift = (const float*)d_in[15];
  const float* W_gamma = (const float*)d_in[16];
  const float* b_gamma = (const float*)d_in[17];
  const float* merge_w = (const float*)d_in[18];

  float* out  = (float*)d_out;          // [B,MW]
  float* neww = out + Bb * MWw;         // [B,H,N] — w_pow scratch then final

  float* ws_f   = (float*)d_ws;
  float* key_ws = ws_f;                     // 65536 floats
  float* params = ws_f + 65536;             // 4096
  float* Zacc   = ws_f + 69632;             // 512
  float* Sacc   = ws_f + 70144;             // 512
  float* e_ws   = ws_f + 70656;             // 4194304
  float* coef   = ws_f + 70656 + 4194304;   // 524288

  hipMemsetAsync(Zacc, 0, 1024 * sizeof(float), stream);    // Z and S
  hipMemsetAsync(out, 0, Bb * MWw * sizeof(float), stream); // out accumulator

  k_params<<<dim3(Bb * Hh), dim3(1024), 0, stream>>>(
      cs, W_head, b_head, W_reset, b_reset, W_key, b_key, W_beta, b_beta,
      W_gate, b_gate, W_shift, b_shift, W_gamma, b_gamma, key_ws, params);
  k_sim<<<dim3(16, Bb), dim3(256), 0, stream>>>(mem, key_ws, params, e_ws, Zacc);
  k_conv<<<dim3(4, Hh, Bb), dim3(256), 0, stream>>>(e_ws, prev, defw, params, Zacc, neww, Sacc);
  k_norm<<<dim3(8, Bb), dim3(256), 0, stream>>>(neww, Sacc, merge_w, coef);
  k_read<<<dim3(16, Bb), dim3(256), 0, stream>>>(mem, coef, out);
}

// Round 3
// 502.572 us; speedup vs baseline: 1.2334x; 1.0060x over previous
//
#include <hip/hip_runtime.h>
#include <hip/hip_bf16.h>
#include <math.h>

#define Bb 64
#define Nn 8192
#define MWw 128
#define Hh 8
#define Cc 1024
#define HDd 128
#define Kk 3

__device__ __forceinline__ float dot4(float4 a, float4 b) {
  return a.x*b.x + a.y*b.y + a.z*b.z + a.w*b.w;
}
__device__ __forceinline__ float sigmoidf_(float x) { return 1.0f / (1.0f + __expf(-x)); }
__device__ __forceinline__ float softplusf_(float x) {
  return fmaxf(x, 0.0f) + log1pf(__expf(-fabsf(x)));
}

// ---------------------------------------------------------------------------
// K1: one block per (b,h), 1024 threads. K-dim split 8 ways, LDS tree reduce.
// ---------------------------------------------------------------------------
__global__ __launch_bounds__(1024) void k_params(
    const float* __restrict__ cs, const float* __restrict__ W_head, const float* __restrict__ b_head,
    const float* __restrict__ W_reset, const float* __restrict__ b_reset,
    const float* __restrict__ W_key, const float* __restrict__ b_key,
    const float* __restrict__ W_beta, const float* __restrict__ b_beta,
    const float* __restrict__ W_gate, const float* __restrict__ b_gate,
    const float* __restrict__ W_shift, const float* __restrict__ b_shift,
    const float* __restrict__ W_gamma, const float* __restrict__ b_gamma,
    float* __restrict__ key_ws, float* __restrict__ params)
{
  int bh = blockIdx.x;
  int b = bh >> 3, h = bh & 7;
  int t = threadIdx.x;
  int d = t & 127, sl = t >> 7;   // 8 slices
  __shared__ float red[8][128];
  __shared__ float head_s[128];
  __shared__ float key_s[128];

  const float* csb = cs + b * Cc + sl * 128;
  const float* w0 = W_head + (size_t)(sl * 128) * (Hh * HDd) + h * HDd + d;
  float acc = 0.0f;
  #pragma unroll 8
  for (int c = 0; c < 128; ++c) acc = fmaf(csb[c], w0[(size_t)c * (Hh * HDd)], acc);
  red[sl][d] = acc;
  __syncthreads();
  if (t < 128) {
    float s = b_head[h * HDd + t];
    #pragma unroll
    for (int j = 0; j < 8; ++j) s += red[j][t];
    head_s[t] = s;
  }
  __syncthreads();

  {
    const float* wk = W_key + (size_t)h * HDd * MWw + (sl * 16) * MWw + d;
    float ka = 0.0f;
    #pragma unroll
    for (int dd = 0; dd < 16; ++dd) ka = fmaf(head_s[sl * 16 + dd], wk[dd * MWw], ka);
    red[sl][d] = ka;
  }
  __syncthreads();
  if (t < 128) {
    float kv = b_key[h * MWw + t];
    #pragma unroll
    for (int j = 0; j < 8; ++j) kv += red[j][t];
    key_ws[bh * MWw + t] = kv;
    key_s[t] = kv;
  }
  __syncthreads();

  float hd = head_s[d];
  float v;
  switch (sl) {
    case 0: v = hd * W_reset[h * HDd + d]; break;
    case 1: v = hd * W_beta[h * HDd + d]; break;
    case 2: v = hd * W_gate[h * HDd + d]; break;
    case 3: v = hd * W_gamma[h * HDd + d]; break;
    case 4: v = hd * W_shift[(h * HDd + d) * Kk + 0]; break;
    case 5: v = hd * W_shift[(h * HDd + d) * Kk + 1]; break;
    case 6: v = hd * W_shift[(h * HDd + d) * Kk + 2]; break;
    default: v = key_s[d] * key_s[d]; break;
  }
  red[sl][d] = v;
  __syncthreads();
  for (int s = 64; s > 0; s >>= 1) {
    if (d < s) red[sl][d] += red[sl][d + s];
    __syncthreads();
  }
  if (t == 0) {
    float reset = sigmoidf_(red[0][0] + b_reset[h]);
    float beta  = softplusf_(red[1][0] + b_beta[h]);
    float gate  = sigmoidf_(red[2][0] + b_gate[h]);
    float gamma = 1.0f + softplusf_(red[3][0] + b_gamma[h]);
    float a0 = red[4][0] + b_shift[h * Kk + 0];
    float a1 = red[5][0] + b_shift[h * Kk + 1];
    float a2 = red[6][0] + b_shift[h * Kk + 2];
    float mx = fmaxf(a0, fmaxf(a1, a2));
    float e0 = __expf(a0 - mx), e1 = __expf(a1 - mx), e2 = __expf(a2 - mx);
    float inv = 1.0f / (e0 + e1 + e2);
    float* P = params + bh * 8;
    P[0] = reset; P[1] = beta; P[2] = gate; P[3] = gamma;
    P[4] = e0 * inv; P[5] = e1 * inv; P[6] = e2 * inv;
    P[7] = sqrtf(red[7][0]);
  }
}

// ---------------------------------------------------------------------------
// K2: big pass 1 over memory. Keys hand-hoisted into 128 VGPRs; #pragma
// unroll 1 outer loop keeps VGPR ~200 (2 waves/EU, no spill). e values are
// staged in LDS (stride 520 -> exactly 2-way banking = free) and written back
// coalesced as float4 (the old per-lane scatter was 32-B-granule, ~2x write
// amplification). atomicAdd Z.
// ---------------------------------------------------------------------------
__global__ __launch_bounds__(256, 2) void k_sim(
    const float* __restrict__ mem, const float* __restrict__ key_ws,
    const float* __restrict__ params, float* __restrict__ e_ws, float* __restrict__ Z)
{
  int b = blockIdx.y, chunk = blockIdx.x;
  int t = threadIdx.x;
  int lane = t & 63, wid = t >> 6;
  int sub = lane & 7, rid = lane >> 3;
  __shared__ float4 keys[8][32];
  __shared__ float betas[8], knorms[8];
  __shared__ float e_s[8][520];   // [head][row-in-chunk], stride 520
  if (t < 8) { betas[t] = params[(b * 8 + t) * 8 + 1]; knorms[t] = params[(b * 8 + t) * 8 + 7]; }
  {
    int h = t >> 5, q = t & 31;
    keys[h][q] = ((const float4*)key_ws)[(b * 8 + h) * 32 + q];
  }
  __syncthreads();

  float4 kreg[8][4];
  #pragma unroll
  for (int h2 = 0; h2 < 8; ++h2) {
    kreg[h2][0] = keys[h2][sub];
    kreg[h2][1] = keys[h2][sub + 8];
    kreg[h2][2] = keys[h2][sub + 16];
    kreg[h2][3] = keys[h2][sub + 24];
  }

  const float4* m4 = (const float4*)mem + (size_t)b * Nn * 32;
  float beta = betas[sub], kn = knorms[sub];
  float zloc = 0.0f;
  int n0 = chunk * 512;

  #pragma unroll 1
  for (int itr = 0; itr < 8; ++itr) {
    int nb = n0 + itr * 64 + wid * 16 + rid;  // row for r=0; r adds 8
    float4 m[2][4];
    float nrm[2];
    float acc[2][8];
    #pragma unroll
    for (int r = 0; r < 2; ++r) {
      const float4* rp = m4 + (size_t)(nb + r * 8) * 32 + sub;
      m[r][0] = rp[0]; m[r][1] = rp[8]; m[r][2] = rp[16]; m[r][3] = rp[24];
    }
    #pragma unroll
    for (int r = 0; r < 2; ++r) {
      nrm[r] = dot4(m[r][0], m[r][0]) + dot4(m[r][1], m[r][1])
             + dot4(m[r][2], m[r][2]) + dot4(m[r][3], m[r][3]);
      #pragma unroll
      for (int h2 = 0; h2 < 8; ++h2) {
        acc[r][h2] = dot4(m[r][0], kreg[h2][0]) + dot4(m[r][1], kreg[h2][1])
                   + dot4(m[r][2], kreg[h2][2]) + dot4(m[r][3], kreg[h2][3]);
      }
    }
    #pragma unroll
    for (int r = 0; r < 2; ++r) {
      float* a = acc[r];
      bool h1 = (sub & 1) != 0;
      float v40 = (h1 ? a[1] : a[0]) + __shfl_xor(h1 ? a[0] : a[1], 1, 64);
      float v41 = (h1 ? a[3] : a[2]) + __shfl_xor(h1 ? a[2] : a[3], 1, 64);
      float v42 = (h1 ? a[5] : a[4]) + __shfl_xor(h1 ? a[4] : a[5], 1, 64);
      float v43 = (h1 ? a[7] : a[6]) + __shfl_xor(h1 ? a[6] : a[7], 1, 64);
      bool h2b = (sub & 2) != 0;
      float v20 = (h2b ? v41 : v40) + __shfl_xor(h2b ? v40 : v41, 2, 64);
      float v21 = (h2b ? v43 : v42) + __shfl_xor(h2b ? v42 : v43, 2, 64);
      bool h4 = (sub & 4) != 0;
      float dsum = (h4 ? v21 : v20) + __shfl_xor(h4 ? v20 : v21, 4, 64);
      float nr = nrm[r];
      nr += __shfl_xor(nr, 1, 64);
      nr += __shfl_xor(nr, 2, 64);
      nr += __shfl_xor(nr, 4, 64);
      float s = beta * dsum / (kn * sqrtf(nr) + 1e-8f);
      float e = __expf(s - beta);
      e_s[sub][(nb + r * 8) - n0] = e;   // lane addr = sub*520 + nloc -> 2-way banks, free
      zloc += e;
    }
  }
  zloc += __shfl_xor(zloc, 8, 64);
  zloc += __shfl_xor(zloc, 16, 64);
  zloc += __shfl_xor(zloc, 32, 64);
  if (lane < 8) atomicAdd(&Z[b * 8 + lane], zloc);
  __syncthreads();

  // coalesced float4 writeback: 8 heads x 512 rows = 1024 float4 / 256 thr
  #pragma unroll
  for (int j = 0; j < 4; ++j) {
    int idx = j * 256 + t;
    int h = idx >> 7, q = idx & 127;
    float4 v = *(const float4*)&e_s[h][q * 4];
    ((float4*)(e_ws + (size_t)(b * 8 + h) * Nn + n0))[q] = v;
  }
}

// ---------------------------------------------------------------------------
// K3: w_g blend + circular conv (K=3) + gamma power, float4 throughout.
// LDS layout: wg[l] = w_g[n0+l] for l in [0,2048); wg[2048] = w_g[n0-1],
// wg[2049] = w_g[n0+2048] (circular halos). Aligned b128 LDS reads.
// w_pow written into d_out's new_w region (normalized in K4). atomicAdd S.
// ---------------------------------------------------------------------------
__global__ __launch_bounds__(256) void k_conv(
    const float* __restrict__ e_ws, const float* __restrict__ prev, const float* __restrict__ defw,
    const float* __restrict__ params, const float* __restrict__ Z,
    float* __restrict__ wp, float* __restrict__ S)
{
  int chunk = blockIdx.x, h = blockIdx.y, b = blockIdx.z;
  int bh = b * 8 + h, t = threadIdx.x;
  __shared__ float wg[2052];
  const float* P = params + bh * 8;
  float reset = P[0], gate = P[2], gamma = P[3], s0 = P[4], s1 = P[5], s2 = P[6];
  float invZg = gate / Z[bh];
  float om = 1.0f - gate, omr = 1.0f - reset;
  size_t base = (size_t)bh * Nn;
  int n0 = chunk * 2048;

  const float4* e4p = (const float4*)(e_ws + base + n0);
  const float4* p4p = (const float4*)(prev + base + n0);
  const float4* d4p = (const float4*)(defw + base + n0);
  #pragma unroll
  for (int it = 0; it < 2; ++it) {
    int idx4 = it * 256 + t;
    float4 e = e4p[idx4], pv = p4p[idx4], dv = d4p[idx4];
    float4 w;
    w.x = invZg * e.x + om * (pv.x * omr + dv.x * reset);
    w.y = invZg * e.y + om * (pv.y * omr + dv.y * reset);
    w.z = invZg * e.z + om * (pv.z * omr + dv.z * reset);
    w.w = invZg * e.w + om * (pv.w * omr + dv.w * reset);
    *(float4*)&wg[idx4 * 4] = w;
  }
  if (t < 2) {
    int n = (t == 0) ? ((n0 + Nn - 1) & (Nn - 1)) : ((n0 + 2048) & (Nn - 1));
    float e = e_ws[base + n], pv = prev[base + n], dv = defw[base + n];
    wg[2048 + t] = invZg * e + om * (pv * omr + dv * reset);
  }
  __syncthreads();

  float sacc = 0.0f;
  float4* wp4 = (float4*)(wp + base + n0);
  #pragma unroll
  for (int it = 0; it < 2; ++it) {
    int idx4 = it * 256 + t;
    int l = idx4 * 4;
    float4 c = *(const float4*)&wg[l];
    float left  = (l == 0)        ? wg[2048] : wg[l - 1];
    float right = (l + 4 == 2048) ? wg[2049] : wg[l + 4];
    // w_s[n] = s0*w_g[n+1] + s1*w_g[n] + s2*w_g[n-1]  (jnp.roll semantics)
    float4 wsv;
    wsv.x = s0 * c.y   + s1 * c.x + s2 * left;
    wsv.y = s0 * c.z   + s1 * c.y + s2 * c.x;
    wsv.z = s0 * c.w   + s1 * c.z + s2 * c.y;
    wsv.w = s0 * right + s1 * c.w + s2 * c.z;
    float4 o;
    o.x = __expf(gamma * __logf(wsv.x + 1e-8f));
    o.y = __expf(gamma * __logf(wsv.y + 1e-8f));
    o.z = __expf(gamma * __logf(wsv.z + 1e-8f));
    o.w = __expf(gamma * __logf(wsv.w + 1e-8f));
    wp4[idx4] = o;
    sacc += o.x + o.y + o.z + o.w;
  }
  sacc += __shfl_xor(sacc, 1, 64);
  sacc += __shfl_xor(sacc, 2, 64);
  sacc += __shfl_xor(sacc, 4, 64);
  sacc += __shfl_xor(sacc, 8, 64);
  sacc += __shfl_xor(sacc, 16, 64);
  sacc += __shfl_xor(sacc, 32, 64);
  __shared__ float sred[4];
  if ((t & 63) == 0) sred[t >> 6] = sacc;
  __syncthreads();
  if (t == 0) atomicAdd(&S[bh], sred[0] + sred[1] + sred[2] + sred[3]);
}

// ---------------------------------------------------------------------------
// K4 (fused norm+read): each block owns 512 rows of batch b.
// Phase 1: normalize new_w in place for all 8 heads, build per-row merged
//          coefficient coef[n] = sum_h (merge_w[h]/S[h]) * w_pow[h,n] in LDS.
// Phase 2: out[b,:] += sum_n coef[n] * mem[b,n,:]  (float4, LDS reduce,
//          128 atomics/block). Kills the separate k_norm pass + coef traffic.
// ---------------------------------------------------------------------------
__global__ __launch_bounds__(256) void k_readnorm(
    const float* __restrict__ mem, float* __restrict__ wp, const float* __restrict__ S,
    const float* __restrict__ merge_w, float* __restrict__ out)
{
  int b = blockIdx.y; int n0 = blockIdx.x * 512; int t = threadIdx.x;
  __shared__ float kh[8], invS_s[8];
  __shared__ float coef_s[512];
  __shared__ float4 red4[256];
  if (t < 8) {
    float s = S[b * 8 + t];
    invS_s[t] = 1.0f / s;
    kh[t] = merge_w[t] / s;
  }
  __syncthreads();

  // Phase 1: normalize + coef
  #pragma unroll
  for (int ii = 0; ii < 2; ++ii) {
    int nl = ii * 256 + t;
    float cf = 0.0f;
    #pragma unroll
    for (int h = 0; h < 8; ++h) {
      size_t idx = (size_t)(b * 8 + h) * Nn + n0 + nl;
      float v = wp[idx];
      wp[idx] = v * invS_s[h];
      cf = fmaf(kh[h], v, cf);
    }
    coef_s[nl] = cf;
  }
  __syncthreads();

  // Phase 2: read pass
  int w4 = t & 31, rg = t >> 5;
  const float4* m4 = (const float4*)mem + (size_t)b * Nn * 32;
  float4 acc = make_float4(0.0f, 0.0f, 0.0f, 0.0f);
  #pragma unroll 4
  for (int it = 0; it < 64; ++it) {
    int nl = it * 8 + rg;
    float c = coef_s[nl];
    float4 m = m4[(size_t)(n0 + nl) * 32 + w4];
    acc.x = fmaf(c, m.x, acc.x);
    acc.y = fmaf(c, m.y, acc.y);
    acc.z = fmaf(c, m.z, acc.z);
    acc.w = fmaf(c, m.w, acc.w);
  }
  red4[t] = acc;
  __syncthreads();
  if (t < 32) {
    float4 s = red4[t];
    #pragma unroll
    for (int j = 1; j < 8; ++j) {
      float4 o = red4[t + 32 * j];
      s.x += o.x; s.y += o.y; s.z += o.z; s.w += o.w;
    }
    atomicAdd(&out[b * MWw + t * 4 + 0], s.x);
    atomicAdd(&out[b * MWw + t * 4 + 1], s.y);
    atomicAdd(&out[b * MWw + t * 4 + 2], s.z);
    atomicAdd(&out[b * MWw + t * 4 + 3], s.w);
  }
}

extern "C" void kernel_launch(void* const* d_in, const int* in_sizes, int n_in,
                              void* d_out, int out_size, void* d_ws, size_t ws_size,
                              hipStream_t stream)
{
  const float* cs      = (const float*)d_in[0];
  const float* mem     = (const float*)d_in[1];
  const float* prev    = (const float*)d_in[2];
  const float* defw    = (const float*)d_in[3];
  const float* W_head  = (const float*)d_in[4];
  const float* b_head  = (const float*)d_in[5];
  const float* W_reset = (const float*)d_in[6];
  const float* b_reset = (const float*)d_in[7];
  const float* W_key   = (const float*)d_in[8];
  const float* b_key   = (const float*)d_in[9];
  const float* W_beta  = (const float*)d_in[10];
  const float* b_beta  = (const float*)d_in[11];
  const float* W_gate  = (const float*)d_in[12];
  const float* b_gate  = (const float*)d_in[13];
  const float* W_shift = (const float*)d_in[14];
  const float* b_shift = (const float*)d_in[15];
  const float* W_gamma = (const float*)d_in[16];
  const float* b_gamma = (const float*)d_in[17];
  const float* merge_w = (const float*)d_in[18];

  float* out  = (float*)d_out;          // [B,MW]
  float* neww = out + Bb * MWw;         // [B,H,N] — w_pow scratch then final

  float* ws_f   = (float*)d_ws;
  float* key_ws = ws_f;                     // 65536 floats
  float* params = ws_f + 65536;             // 4096
  float* Zacc   = ws_f + 69632;             // 512
  float* Sacc   = ws_f + 70144;             // 512
  float* e_ws   = ws_f + 70656;             // 4194304

  hipMemsetAsync(Zacc, 0, 1024 * sizeof(float), stream);    // Z and S
  hipMemsetAsync(out, 0, Bb * MWw * sizeof(float), stream); // out accumulator

  k_params<<<dim3(Bb * Hh), dim3(1024), 0, stream>>>(
      cs, W_head, b_head, W_reset, b_reset, W_key, b_key, W_beta, b_beta,
      W_gate, b_gate, W_shift, b_shift, W_gamma, b_gamma, key_ws, params);
  k_sim<<<dim3(16, Bb), dim3(256), 0, stream>>>(mem, key_ws, params, e_ws, Zacc);
  k_conv<<<dim3(4, Hh, Bb), dim3(256), 0, stream>>>(e_ws, prev, defw, params, Zacc, neww, Sacc);
  k_readnorm<<<dim3(16, Bb), dim3(256), 0, stream>>>(mem, neww, Sacc, merge_w, out);
}